// Round 4
// baseline (933.540 us; speedup 1.0000x reference)
//
#include <hip/hip_runtime.h>
#include <stdint.h>

#define T_TOK 8192
#define DM 1024
#define HID 4096
#define NE 8
#define RP2 18432      // 16384 + 8*256 worst-case rows padded to 256
#define MT128 144      // RP2 / 128
#define MT256 72       // RP2 / 256

typedef unsigned short u16;
typedef __attribute__((ext_vector_type(4))) float f32x4;
typedef __attribute__((ext_vector_type(8))) __bf16 bf16x8;

#define GLB(p) ((const __attribute__((address_space(1))) unsigned int*)(p))
#define LDSP(p) ((__attribute__((address_space(3))) unsigned int*)(p))

__device__ __forceinline__ u16 f2bf(float f) {
    union { float f; unsigned u; } c; c.f = f;
    unsigned r = (c.u + 0x7FFFu + ((c.u >> 16) & 1u)) >> 16;
    return (u16)r;
}

template<int Nw> __device__ __forceinline__ void vmwait() {
    if constexpr (Nw == 0)       asm volatile("s_waitcnt vmcnt(0)" ::: "memory");
    else if constexpr (Nw == 2)  asm volatile("s_waitcnt vmcnt(2)" ::: "memory");
    else if constexpr (Nw == 4)  asm volatile("s_waitcnt vmcnt(4)" ::: "memory");
    else if constexpr (Nw == 6)  asm volatile("s_waitcnt vmcnt(6)" ::: "memory");
    else if constexpr (Nw == 8)  asm volatile("s_waitcnt vmcnt(8)" ::: "memory");
    else if constexpr (Nw == 12) asm volatile("s_waitcnt vmcnt(12)" ::: "memory");
}

// ---------- 0: zero counters ----------
__global__ void k_zero(int* counts, int* cursors) {
    if (threadIdx.x < NE) { counts[threadIdx.x] = 0; cursors[threadIdx.x] = 0; }
}

// ---------- 1: gating (one wave per token, fp32) ----------
__global__ __launch_bounds__(256) void k_gate(const float* __restrict__ x,
        const float* __restrict__ gw, const float* __restrict__ gb,
        int* __restrict__ tok_e, float* __restrict__ tok_w, int* __restrict__ counts) {
    int t = blockIdx.x * 4 + (threadIdx.x >> 6);
    int lane = threadIdx.x & 63;
    const float* xr = x + (size_t)t * DM;
    float a0=0,a1=0,a2=0,a3=0,a4=0,a5=0,a6=0,a7=0;
    for (int d = lane; d < DM; d += 64) {
        float xv = xr[d];
        const float4* g = (const float4*)(gw + (size_t)d * NE);
        float4 g0 = g[0], g1 = g[1];
        a0 += xv*g0.x; a1 += xv*g0.y; a2 += xv*g0.z; a3 += xv*g0.w;
        a4 += xv*g1.x; a5 += xv*g1.y; a6 += xv*g1.z; a7 += xv*g1.w;
    }
    #pragma unroll
    for (int off = 32; off; off >>= 1) {
        a0 += __shfl_xor(a0, off); a1 += __shfl_xor(a1, off);
        a2 += __shfl_xor(a2, off); a3 += __shfl_xor(a3, off);
        a4 += __shfl_xor(a4, off); a5 += __shfl_xor(a5, off);
        a6 += __shfl_xor(a6, off); a7 += __shfl_xor(a7, off);
    }
    if (lane == 0) {
        float l[8] = {a0+gb[0],a1+gb[1],a2+gb[2],a3+gb[3],a4+gb[4],a5+gb[5],a6+gb[6],a7+gb[7]};
        int e0 = 0;
        #pragma unroll
        for (int e = 1; e < 8; ++e) if (l[e] > l[e0]) e0 = e;
        int e1 = (e0 == 0) ? 1 : 0;
        #pragma unroll
        for (int e = 0; e < 8; ++e) if (e != e0 && l[e] > l[e1]) e1 = e;
        float p1 = expf(l[e1] - l[e0]);
        float inv = 1.f / (1.f + p1);
        tok_e[2*t] = e0; tok_e[2*t+1] = e1;
        tok_w[2*t] = inv; tok_w[2*t+1] = p1 * inv;
        atomicAdd(&counts[e0], 1);
        atomicAdd(&counts[e1], 1);
    }
}

// ---------- 2: padded prefix (256-aligned) + tile->expert map (128-granular) ----------
__global__ void k_scan(const int* __restrict__ counts, int* __restrict__ pad_off,
                       int* __restrict__ tile_expert, int* __restrict__ row_token) {
    __shared__ int off[NE + 1];
    if (threadIdx.x == 0) {
        int o = 0;
        for (int e = 0; e < NE; ++e) { off[e] = o; pad_off[e] = o; o += ((counts[e] + 255) >> 8) << 8; }
        off[NE] = o; pad_off[NE] = o;
    }
    __syncthreads();
    for (int i = threadIdx.x; i < MT128; i += blockDim.x) {
        int ex = -1, base = i * 128;
        #pragma unroll
        for (int e = 0; e < NE; ++e) if (base >= off[e] && base < off[e+1]) ex = e;
        tile_expert[i] = ex;
    }
    for (int i = threadIdx.x; i < RP2; i += blockDim.x) row_token[i] = -1;
}

// ---------- 3: assign rows ----------
__global__ __launch_bounds__(256) void k_assign(const int* __restrict__ tok_e, const float* __restrict__ tok_w,
        const int* __restrict__ pad_off, int* __restrict__ cursors,
        int* __restrict__ row_token, float* __restrict__ row_weight, int* __restrict__ token_rows) {
    int t = blockIdx.x * 256 + threadIdx.x;
    if (t >= T_TOK) return;
    #pragma unroll
    for (int k = 0; k < 2; ++k) {
        int e = tok_e[2*t+k];
        int pos = atomicAdd(&cursors[e], 1);
        int r = pad_off[e] + pos;
        row_token[r] = t;
        row_weight[r] = tok_w[2*t+k];
        token_rows[2*t+k] = r;
    }
}

// ---------- 4: x fp32 -> bf16 ----------
__global__ __launch_bounds__(256) void k_convx(const float* __restrict__ x, u16* __restrict__ xb) {
    size_t i = ((size_t)blockIdx.x * 256 + threadIdx.x) * 8;
    const float4* p = (const float4*)(x + i);
    float4 v0 = p[0], v1 = p[1];
    uint4 o;
    o.x = f2bf(v0.x) | ((unsigned)f2bf(v0.y) << 16);
    o.y = f2bf(v0.z) | ((unsigned)f2bf(v0.w) << 16);
    o.z = f2bf(v1.x) | ((unsigned)f2bf(v1.y) << 16);
    o.w = f2bf(v1.z) | ((unsigned)f2bf(v1.w) << 16);
    *(uint4*)(xb + i) = o;
}

// ---------- 5: weight transpose+convert: [E][R][C] f32 -> [E][C][R] bf16 ----------
template<int R, int C>
__global__ __launch_bounds__(256) void k_transpose(const float* __restrict__ in, u16* __restrict__ out) {
    __shared__ u16 lds[64][260];
    const int TR = R / 256, TC = C / 64;
    const int tiles = TR * TC;
    int e = blockIdx.x / tiles;
    int rem = blockIdx.x % tiles;
    int rt = rem / TC, ct = rem % TC;
    const float* src = in + (size_t)e * R * C + (size_t)rt * 256 * C + ct * 64;
    u16* dst = out + (size_t)e * R * C + (size_t)ct * 64 * R + rt * 256;
    int t = threadIdx.x;
    #pragma unroll
    for (int i = 0; i < 16; ++i) {
        int o = i * 256 + t;
        int r = o >> 4;
        int c4 = (o & 15) * 4;
        float4 v = *(const float4*)&src[(size_t)r * C + c4];
        lds[c4+0][r] = f2bf(v.x);
        lds[c4+1][r] = f2bf(v.y);
        lds[c4+2][r] = f2bf(v.z);
        lds[c4+3][r] = f2bf(v.w);
    }
    __syncthreads();
    #pragma unroll
    for (int i = 0; i < 16; ++i) {
        int o = i * 256 + t;
        int c = o >> 6;
        int r4 = (o & 63) * 4;
        ushort4 u;
        u.x = lds[c][r4+0]; u.y = lds[c][r4+1];
        u.z = lds[c][r4+2]; u.w = lds[c][r4+3];
        *(ushort4*)&dst[(size_t)c * R + r4] = u;
    }
}

// ---------- 6: ring-4 counted-vmcnt MoE GEMM (BK=32, 8 waves 2x4) ----------
// T1 XCD-chunked swizzle + T2 both-sides XOR swizzle + T3/T4 ring-of-4 LDS
// with counted vmcnt (stage 3 K-tiles ahead, never drain to 0 mid-loop) +
// T5 setprio around the MFMA cluster. Raw s_barrier (NOT __syncthreads —
// its implicit vmcnt(0) would kill the pipeline) + sched_barrier fences.
template<int BM, int BN, int N, int K, bool GATHER, bool SILU>
__global__ __launch_bounds__(512, 2) void k_rgemm(
    const u16* __restrict__ Asrc, const u16* __restrict__ Bw,
    const float* __restrict__ bias, void* __restrict__ Out,
    const int* __restrict__ row_token, const int* __restrict__ tile_expert, int mt)
{
    constexpr int MF = BM / 32;        // m-frags per wave (wr splits BM in 2)
    constexpr int NF = BN / 64;        // n-frags per wave (wc splits BN in 4)
    constexpr int LA = BM / 128;       // A gload_lds per thread per tile
    constexpr int LB = BN / 128;
    constexpr int L  = LA + LB;
    constexpr int NT = K / 32;
    constexpr int NBN = N / BN;

    int id = blockIdx.x;
    int cpx = (NBN * mt) >> 3;
    int sid = (id & 7) * cpx + (id >> 3);
    int bm = sid / NBN, bn = sid % NBN;
    int e = tile_expert[bm * (BM / 128)];
    if (e < 0) return;
    int tid = threadIdx.x, wid = tid >> 6, lane = tid & 63;
    int wr = wid >> 2, wc = wid & 3;

    __shared__ u16 Asl[4 * BM * 32];   // 4 ring slots, BM x 32k bf16 each
    __shared__ u16 Bsl[4 * BN * 32];

    // staging sources: load l covers rows l*128 + wid*16 + (lane>>2),
    // 16B k-slot pre-swizzled: g_ks = (lane&3) ^ (row&3), row&3 = (lane>>2)&3
    unsigned kslb = (unsigned)(((lane & 3) ^ ((lane >> 2) & 3)) * 16);
    const char* aptr[LA];
    const char* bptr[LB];
    #pragma unroll
    for (int l = 0; l < LA; ++l) {
        int row = l * 128 + wid * 16 + (lane >> 2);
        size_t arow;
        if (GATHER) {
            int tk = row_token[bm * BM + row];
            if (tk < 0) tk = 0;        // pad rows: duplicate token 0 (ignored)
            arow = (size_t)tk;
        } else {
            arow = (size_t)(bm * BM + row);
        }
        aptr[l] = (const char*)Asrc + arow * (K * 2) + kslb;
    }
    #pragma unroll
    for (int l = 0; l < LB; ++l) {
        int row = l * 128 + wid * 16 + (lane >> 2);
        bptr[l] = (const char*)Bw + ((size_t)e * N + (size_t)(bn * BN + row)) * (K * 2) + kslb;
    }

    f32x4 acc[MF][NF];
    #pragma unroll
    for (int m = 0; m < MF; ++m)
        #pragma unroll
        for (int n = 0; n < NF; ++n) acc[m][n] = f32x4{0.f, 0.f, 0.f, 0.f};

    auto stage = [&](int buf, int kt) {
        unsigned ko = (unsigned)kt * 64u;
        #pragma unroll
        for (int l = 0; l < LA; ++l)
            __builtin_amdgcn_global_load_lds(GLB(aptr[l] + ko),
                LDSP(Asl + buf * (BM * 32) + (l * 512 + wid * 64) * 8), 16, 0, 0);
        #pragma unroll
        for (int l = 0; l < LB; ++l)
            __builtin_amdgcn_global_load_lds(GLB(bptr[l] + ko),
                LDSP(Bsl + buf * (BN * 32) + (l * 512 + wid * 64) * 8), 16, 0, 0);
    };

    auto compute = [&](int buf) {
        const char* Ab = (const char*)(Asl + buf * (BM * 32));
        const char* Bb = (const char*)(Bsl + buf * (BN * 32));
        unsigned slb = (unsigned)((((lane >> 4) ^ (lane & 3))) * 16);
        bf16x8 bfr[NF];
        #pragma unroll
        for (int n = 0; n < NF; ++n)
            bfr[n] = *(const bf16x8*)(Bb + (wc * (BN / 4) + n * 16 + (lane & 15)) * 64 + slb);
        __builtin_amdgcn_s_setprio(1);
        #pragma unroll
        for (int m = 0; m < MF; ++m) {
            bf16x8 a = *(const bf16x8*)(Ab + (wr * (BM / 2) + m * 16 + (lane & 15)) * 64 + slb);
            #pragma unroll
            for (int n = 0; n < NF; ++n)
                acc[m][n] = __builtin_amdgcn_mfma_f32_16x16x32_bf16(a, bfr[n], acc[m][n], 0, 0, 0);
        }
        __builtin_amdgcn_s_setprio(0);
    };

    // prologue: 3 tiles in flight
    stage(0, 0); stage(1, 1); stage(2, 2);
    for (int kt = 0; kt < NT; ++kt) {
        if (kt + 3 < NT) { stage((kt + 3) & 3, kt + 3); vmwait<3 * L>(); }
        else if (kt + 2 < NT) vmwait<2 * L>();
        else if (kt + 1 < NT) vmwait<L>();
        else vmwait<0>();
        __builtin_amdgcn_s_barrier();      // all waves' tile-kt loads retired
        __builtin_amdgcn_sched_barrier(0);
        compute(kt & 3);
        __builtin_amdgcn_sched_barrier(0);
        __builtin_amdgcn_s_barrier();      // all reads of buf kt&3 done before clobber
    }

    // epilogue: C row=(lane>>4)*4+reg, col=lane&15
    int rb = bm * BM + wr * (BM / 2) + (lane >> 4) * 4;
    int cb = bn * BN + wc * (BN / 4) + (lane & 15);
    #pragma unroll
    for (int n = 0; n < NF; ++n) {
        int col = cb + n * 16;
        float bv = bias[e * N + col];
        #pragma unroll
        for (int m = 0; m < MF; ++m) {
            #pragma unroll
            for (int r = 0; r < 4; ++r) {
                int row = rb + m * 16 + r;
                float v = acc[m][n][r] + bv;
                if (SILU) {
                    v = v / (1.f + __expf(-v));
                    ((u16*)Out)[(size_t)row * N + col] = f2bf(v);
                } else {
                    ((float*)Out)[(size_t)row * N + col] = v;
                }
            }
        }
    }
}

// ---------- 7: combine (one block per token, float4) ----------
__global__ __launch_bounds__(256) void k_combine(const float* __restrict__ ybuf,
        const int* __restrict__ token_rows, const float* __restrict__ row_weight,
        float* __restrict__ out) {
    int t = blockIdx.x;
    int d = threadIdx.x * 4;
    int r0 = token_rows[2*t], r1 = token_rows[2*t+1];
    float w0 = row_weight[r0], w1 = row_weight[r1];
    const float4 y0 = *(const float4*)&ybuf[(size_t)r0 * DM + d];
    const float4 y1 = *(const float4*)&ybuf[(size_t)r1 * DM + d];
    float4 o;
    o.x = w0*y0.x + w1*y1.x;
    o.y = w0*y0.y + w1*y1.y;
    o.z = w0*y0.z + w1*y1.z;
    o.w = w0*y0.w + w1*y1.w;
    *(float4*)&out[(size_t)t * DM + d] = o;
}

extern "C" void kernel_launch(void* const* d_in, const int* in_sizes, int n_in,
                              void* d_out, int out_size, void* d_ws, size_t ws_size,
                              hipStream_t stream) {
    const float* x  = (const float*)d_in[0];
    const float* gw = (const float*)d_in[1];
    const float* gb = (const float*)d_in[2];
    const float* w1 = (const float*)d_in[3];
    const float* b1 = (const float*)d_in[4];
    const float* w2 = (const float*)d_in[5];
    const float* b2 = (const float*)d_in[6];
    float* out = (float*)d_out;

    char* ws = (char*)d_ws;
    size_t off = 0;
    auto alloc = [&](size_t bytes) -> void* {
        void* p = ws + off; off = (off + bytes + 255) & ~(size_t)255; return p;
    };
    // ybuf (written by GEMM2) aliases w1t+xb, dead after GEMM1 (stream-ordered).
    u16*   w1t  = (u16*)alloc((size_t)NE * DM * HID * 2);   // 67.1 MB
    u16*   xb   = (u16*)alloc((size_t)T_TOK * DM * 2);      // 16.8 MB
    u16*   w2t  = (u16*)alloc((size_t)NE * DM * HID * 2);   // 67.1 MB
    u16*   hbuf = (u16*)alloc((size_t)RP2 * HID * 2);       // 151 MB
    int*   tok_e = (int*)alloc(2 * T_TOK * 4);
    float* tok_w = (float*)alloc(2 * T_TOK * 4);
    int*   counts  = (int*)alloc(64);
    int*   cursors = (int*)alloc(64);
    int*   pad_off = (int*)alloc(64);
    int*   row_token  = (int*)alloc(RP2 * 4);
    float* row_weight = (float*)alloc(RP2 * 4);
    int*   token_rows = (int*)alloc(2 * T_TOK * 4);
    int*   tile_expert = (int*)alloc(MT128 * 4);
    float* ybuf = (float*)w1t;                              // 75.5 MB alias

    k_zero<<<1, 64, 0, stream>>>(counts, cursors);
    k_gate<<<T_TOK/4, 256, 0, stream>>>(x, gw, gb, tok_e, tok_w, counts);
    k_scan<<<1, 256, 0, stream>>>(counts, pad_off, tile_expert, row_token);
    k_assign<<<T_TOK/256, 256, 0, stream>>>(tok_e, tok_w, pad_off, cursors, row_token, row_weight, token_rows);
    k_convx<<<(T_TOK*DM)/(256*8), 256, 0, stream>>>(x, xb);
    k_transpose<DM, HID><<<NE*(DM/256)*(HID/64), 256, 0, stream>>>(w1, w1t);
    k_transpose<HID, DM><<<NE*(HID/256)*(DM/64), 256, 0, stream>>>(w2, w2t);
    k_rgemm<256, 256, HID, DM, true, true><<<(HID/256)*MT256, 512, 0, stream>>>(
        xb, w1t, b1, (void*)hbuf, row_token, tile_expert, MT256);
    k_rgemm<128, 128, DM, HID, false, false><<<(DM/128)*MT128, 512, 0, stream>>>(
        hbuf, w2t, b2, (void*)ybuf, row_token, tile_expert, MT128);
    k_combine<<<T_TOK, 256, 0, stream>>>(ybuf, token_rows, row_weight, out);
}